// Round 7
// baseline (346.333 us; speedup 1.0000x reference)
//
#include <hip/hip_runtime.h>

// MultiHeadSelfAttention: B=4, S=2048, D=1024, H=16, HD=64, causal. fp32 I/O, bf16 MFMA.
// R7: GEMM = single-barrier double-buffered K-loop (staging issued post-barrier ->
// ~1 MFMA-phase of latency slack; fp32-A register-prefetch+pack, B/A async dbuf).
// attn = R5 16x16 structure (8 independent accumulators) + swizzled Ks/Vt staging +
// register K/V prefetch across tiles + grid (16,64) heavy-first (4 blocks/CU).

typedef short s16;
typedef __attribute__((ext_vector_type(8))) short bf16x8;
typedef __attribute__((ext_vector_type(4))) float f32x4;

__device__ __forceinline__ s16 f2bf(float f) {
    union { float f; unsigned int i; } v;
    v.f = f;
    unsigned int r = v.i + 0x7fffu + ((v.i >> 16) & 1u);  // RNE
    return (s16)(r >> 16);
}

// pack two fp32 -> bf16x2 dword (round-half-up)
__device__ __forceinline__ unsigned pack_bf16(float a, float b) {
    union { float f; unsigned u; } x, y;
    x.f = a; y.f = b;
    return __byte_perm(x.u + 0x8000u, y.u + 0x8000u, 0x7632);
}

__device__ __forceinline__ bf16x8 pack8(float4 a, float4 b) {
    union { unsigned u[4]; bf16x8 v; } cv;
    cv.u[0] = pack_bf16(a.x, a.y);
    cv.u[1] = pack_bf16(a.z, a.w);
    cv.u[2] = pack_bf16(b.x, b.y);
    cv.u[3] = pack_bf16(b.z, b.w);
    return cv.v;
}

__device__ __forceinline__ void load_lds16(const s16* g, s16* lds_base) {
    __builtin_amdgcn_global_load_lds(
        (const __attribute__((address_space(1))) void*)g,
        (__attribute__((address_space(3))) void*)lds_base, 16, 0, 0);
}

// ---------------------------------------------------------------------------
// Transpose + cast: fp32 [R,C] -> bf16 [C,R]
// ---------------------------------------------------------------------------
__global__ void transpose_cast(const float* __restrict__ in,
                               s16* __restrict__ out, int R, int C) {
    __shared__ float tile[32][33];
    const int cb = blockIdx.x * 32, rb = blockIdx.y * 32;
    const int tx = threadIdx.x, ty = threadIdx.y;  // 32 x 8
#pragma unroll
    for (int i = 0; i < 32; i += 8)
        tile[ty + i][tx] = in[(size_t)(rb + ty + i) * C + cb + tx];
    __syncthreads();
#pragma unroll
    for (int i = 0; i < 32; i += 8)
        out[(size_t)(cb + ty + i) * R + rb + tx] = f2bf(tile[tx][ty + i]);
}

// ---------------------------------------------------------------------------
// C[M,N] = A[M,K] @ Bt[N,K]^T + bias[N]. 128x128 tile, BK=32, double-buffered
// single-barrier K-loop. A fp32 (register prefetch + pack) or bf16 (async dbuf);
// Bt async dbuf. All staging for k+1 issued AFTER the barrier of step k.
// ---------------------------------------------------------------------------
template <bool A_F32, bool OUT_F32>
__global__ __launch_bounds__(256) void gemm_bt_bias(
    const void* __restrict__ Av,
    const s16* __restrict__ Bt,
    const float* __restrict__ bias,
    void* __restrict__ Cv,
    int M, int N, int K) {
    __shared__ __attribute__((aligned(16))) s16 As[2 * 4096];
    __shared__ __attribute__((aligned(16))) s16 Bs[2 * 4096];

    const int tid  = threadIdx.x;
    const int lane = tid & 63;
    const int wave = tid >> 6;
    const int l15  = lane & 15;
    const int quad = lane >> 4;
    const int m0 = blockIdx.y * 128;
    const int n0 = blockIdx.x * 128;
    const int wm = (wave & 1) * 64;
    const int wn = (wave >> 1) * 64;

    f32x4 acc[4][4];
#pragma unroll
    for (int i = 0; i < 4; ++i)
#pragma unroll
        for (int j = 0; j < 4; ++j)
            acc[i][j] = (f32x4){0.f, 0.f, 0.f, 0.f};

    const int r_a = tid >> 2;  // 0..63 row in 64-row chunk
    const int kp  = tid & 3;
    const float* Af = (const float*)Av;
    const s16*   Ab = (const s16*)Av;

    float4 pfa[2][2];
    // prologue: stage k=0
#pragma unroll
    for (int c = 0; c < 2; ++c) {
        if constexpr (A_F32) {
            const float4* p = (const float4*)(Af + (size_t)(m0 + c * 64 + r_a) * K + kp * 8);
            pfa[c][0] = p[0]; pfa[c][1] = p[1];
        } else {
            load_lds16(Ab + (size_t)(m0 + c * 64 + r_a) * K + kp * 8, As + c * 2048 + wave * 512);
        }
        load_lds16(Bt + (size_t)(n0 + c * 64 + r_a) * K + kp * 8, Bs + c * 2048 + wave * 512);
    }

    const int nk = K >> 5;
    for (int it = 0; it < nk; ++it) {
        const int cur = it & 1;
        if constexpr (A_F32) {
            // pack & store tile-it A (pfa loaded one iteration ago -> latency hidden)
#pragma unroll
            for (int c = 0; c < 2; ++c) {
                const bf16x8 va = pack8(pfa[c][0], pfa[c][1]);
                *(bf16x8*)(As + cur * 4096 + (c * 64 + r_a) * 32 + kp * 8) = va;
            }
        }
        __syncthreads();  // tile-it staging visible; readers of buf cur^1 done

        if (it + 1 < nk) {  // stage k+1 into buf cur^1 (drained at next barrier)
            const int k1 = (it + 1) * 32;
#pragma unroll
            for (int c = 0; c < 2; ++c) {
                if constexpr (A_F32) {
                    const float4* p = (const float4*)(Af + (size_t)(m0 + c * 64 + r_a) * K + k1 + kp * 8);
                    pfa[c][0] = p[0]; pfa[c][1] = p[1];
                } else {
                    load_lds16(Ab + (size_t)(m0 + c * 64 + r_a) * K + k1 + kp * 8,
                               As + (cur ^ 1) * 4096 + c * 2048 + wave * 512);
                }
                load_lds16(Bt + (size_t)(n0 + c * 64 + r_a) * K + k1 + kp * 8,
                           Bs + (cur ^ 1) * 4096 + c * 2048 + wave * 512);
            }
        }

        const s16* Asb = As + cur * 4096;
        const s16* Bsb = Bs + cur * 4096;
        bf16x8 af[4], bfv[4];
#pragma unroll
        for (int mt = 0; mt < 4; ++mt)
            af[mt] = *(const bf16x8*)(Asb + (wm + mt * 16 + l15) * 32 + quad * 8);
#pragma unroll
        for (int nt = 0; nt < 4; ++nt)
            bfv[nt] = *(const bf16x8*)(Bsb + (wn + nt * 16 + l15) * 32 + quad * 8);
#pragma unroll
        for (int mt = 0; mt < 4; ++mt)
#pragma unroll
            for (int nt = 0; nt < 4; ++nt)
                acc[mt][nt] = __builtin_amdgcn_mfma_f32_16x16x32_bf16(af[mt], bfv[nt], acc[mt][nt], 0, 0, 0);
    }

#pragma unroll
    for (int nt = 0; nt < 4; ++nt) {
        const int col = n0 + wn + nt * 16 + l15;
        const float bv = bias[col];
#pragma unroll
        for (int mt = 0; mt < 4; ++mt) {
            const int rowb = m0 + wm + mt * 16 + quad * 4;
#pragma unroll
            for (int r = 0; r < 4; ++r) {
                const float v = acc[mt][nt][r] + bv;
                if constexpr (OUT_F32)
                    ((float*)Cv)[(size_t)(rowb + r) * N + col] = v;
                else
                    ((s16*)Cv)[(size_t)(rowb + r) * N + col] = f2bf(v);
            }
        }
    }
}

// ---------------------------------------------------------------------------
// Flash attention (causal), 16x16x32 MFMA, fixed-M softmax. One q-tile (128 rows)
// per block, grid (16,64) heavy-first. K/V register-prefetched across tiles.
// Ks [64][72] + Vt [64][72] (transposed) both granule-XOR swizzled (R6-verified);
// Ps per-wave roundtrip [16][80] (R5-verified).
// ---------------------------------------------------------------------------
__global__ __launch_bounds__(256) void attn_fwd(
    const s16* __restrict__ qkv,
    s16* __restrict__ attn) {
    __shared__ __attribute__((aligned(16))) s16 Ks[64 * 72];
    __shared__ __attribute__((aligned(16))) s16 Vt[64 * 72];
    __shared__ __attribute__((aligned(16))) s16 Ps[4][2][16][80];

    const int tid  = threadIdx.x;
    const int lane = tid & 63;
    const int wave = tid >> 6;
    const int l15  = lane & 15;
    const int quad = lane >> 4;
    const int bh = blockIdx.y;
    const size_t rowbase = (size_t)(bh >> 4) * 2048;
    const int hoff = (bh & 15) * 64;
    const int kp  = tid >> 3;  // 0..31: staged key-pair {2kp, 2kp+1}
    const int p_s = tid & 7;   // hd granule
    const int kg  = kp >> 2;   // key granule of this thread's pair

    const float C2 = 0.18033688011112042f;  // 0.125 * log2(e)
    const float M2 = 12.0f;                 // fixed shift (softmax shift-invariant)

    const int qt = 15 - (int)blockIdx.x;    // heavy blocks dispatched first
    const int wq = qt * 128 + wave * 32;

    // Q fragments (A-operand) in registers for the whole key loop.
    bf16x8 qf[2][2];
#pragma unroll
    for (int mt = 0; mt < 2; ++mt)
#pragma unroll
        for (int ks = 0; ks < 2; ++ks)
            qf[mt][ks] = *(const bf16x8*)(qkv + (rowbase + wq + mt * 16 + l15) * 3072 + hoff + ks * 32 + quad * 8);

    float l_lane[2][4];
    f32x4 o[2][4];
#pragma unroll
    for (int mt = 0; mt < 2; ++mt) {
#pragma unroll
        for (int r = 0; r < 4; ++r) l_lane[mt][r] = 0.f;
#pragma unroll
        for (int n = 0; n < 4; ++n) o[mt][n] = (f32x4){0.f, 0.f, 0.f, 0.f};
    }

    const int nkt = qt * 2 + 2;
    // prefetch tile 0 K/V into registers
    bf16x8 kv[2], vv[2];
#pragma unroll
    for (int dk = 0; dk < 2; ++dk) {
        const s16* g = qkv + (rowbase + 2 * kp + dk) * 3072 + hoff + p_s * 8;
        kv[dk] = *(const bf16x8*)(g + 1024);
        vv[dk] = *(const bf16x8*)(g + 2048);
    }

    for (int kt = 0; kt < nkt; ++kt) {
        const int k0 = kt * 64;
        __syncthreads();  // prev iteration's LDS reads done
#pragma unroll
        for (int dk = 0; dk < 2; ++dk) {  // store prefetched K (swizzled)
            const int k = 2 * kp + dk;
            *(bf16x8*)(Ks + k * 72 + ((p_s ^ kg) << 3)) = kv[dk];
        }
#pragma unroll
        for (int j = 0; j < 8; ++j) {  // V transposed: Vt[hd][key] pairs, b32 each
            const unsigned dw = (unsigned)(unsigned short)vv[0][j] |
                                ((unsigned)(unsigned short)vv[1][j] << 16);
            *(unsigned*)(Vt + (p_s * 8 + j) * 72 + ((kg ^ p_s) << 3) + (2 * kp & 7)) = dw;
        }
        __syncthreads();

        if (kt + 1 < nkt) {  // prefetch next tile (latency hidden under compute)
#pragma unroll
            for (int dk = 0; dk < 2; ++dk) {
                const s16* g = qkv + (rowbase + k0 + 64 + 2 * kp + dk) * 3072 + hoff + p_s * 8;
                kv[dk] = *(const bf16x8*)(g + 1024);
                vv[dk] = *(const bf16x8*)(g + 2048);
            }
        }

        if (k0 > wq + 31) continue;  // fully masked for this wave (barriers done)

        // S = Q K^T  (32q x 64k per wave)
        f32x4 sc[2][4];
#pragma unroll
        for (int mt = 0; mt < 2; ++mt)
#pragma unroll
            for (int nt = 0; nt < 4; ++nt)
                sc[mt][nt] = (f32x4){0.f, 0.f, 0.f, 0.f};
#pragma unroll
        for (int nt = 0; nt < 4; ++nt)
#pragma unroll
            for (int ks = 0; ks < 2; ++ks) {
                const int keyg = 2 * nt + (l15 >> 3);  // key-row granule
                const bf16x8 kf = *(const bf16x8*)(
                    Ks + (nt * 16 + l15) * 72 + (((ks * 4 + quad) ^ keyg) << 3));
#pragma unroll
                for (int mt = 0; mt < 2; ++mt)
                    sc[mt][nt] = __builtin_amdgcn_mfma_f32_16x16x32_bf16(qf[mt][ks], kf, sc[mt][nt], 0, 0, 0);
            }

        const bool edge = (k0 + 63 > wq);  // tile touches the causal boundary
#pragma unroll
        for (int mt = 0; mt < 2; ++mt)
#pragma unroll
            for (int nt = 0; nt < 4; ++nt) {
                const int key = k0 + nt * 16 + l15;
#pragma unroll
                for (int r = 0; r < 4; ++r) {
                    float t = fmaf(sc[mt][nt][r], C2, -M2);
                    if (edge) {
                        const int qrow = wq + mt * 16 + quad * 4 + r;
                        t = (key <= qrow) ? t : -150.f;  // exp2(-150) == 0
                    }
                    const float p = __builtin_amdgcn_exp2f(t);
                    l_lane[mt][r] += p;
                    Ps[wave][mt][quad * 4 + r][nt * 16 + l15] = f2bf(p);
                }
            }

        // O += P V  (P roundtrip via per-wave LDS; V^T b128 swizzled fragments)
#pragma unroll
        for (int ks = 0; ks < 2; ++ks) {
            bf16x8 pf[2];
#pragma unroll
            for (int mt = 0; mt < 2; ++mt)
                pf[mt] = *(const bf16x8*)(&Ps[wave][mt][l15][ks * 32 + quad * 8]);
#pragma unroll
            for (int n = 0; n < 4; ++n) {
                const int hdg = 2 * n + (l15 >> 3);  // hd-row granule
                const bf16x8 vf = *(const bf16x8*)(
                    Vt + (n * 16 + l15) * 72 + (((ks * 4 + quad) ^ hdg) << 3));
#pragma unroll
                for (int mt = 0; mt < 2; ++mt)
                    o[mt][n] = __builtin_amdgcn_mfma_f32_16x16x32_bf16(pf[mt], vf, o[mt][n], 0, 0, 0);
            }
        }
    }

    // final l reduction across the 16 replicated lanes
#pragma unroll
    for (int mt = 0; mt < 2; ++mt)
#pragma unroll
        for (int r = 0; r < 4; ++r)
#pragma unroll
            for (int d = 1; d < 16; d <<= 1)
                l_lane[mt][r] += __shfl_xor(l_lane[mt][r], d);

#pragma unroll
    for (int mt = 0; mt < 2; ++mt)
#pragma unroll
        for (int n = 0; n < 4; ++n)
#pragma unroll
            for (int r = 0; r < 4; ++r) {
                const int qrow = wq + mt * 16 + quad * 4 + r;
                attn[(rowbase + qrow) * 1024 + hoff + n * 16 + l15] = f2bf(o[mt][n][r] / l_lane[mt][r]);
            }
}

// ---------------------------------------------------------------------------
extern "C" void kernel_launch(void* const* d_in, const int* in_sizes, int n_in,
                              void* d_out, int out_size, void* d_ws, size_t ws_size,
                              hipStream_t stream) {
    const float* x    = (const float*)d_in[0];  // [8192,1024]
    const float* Wqkv = (const float*)d_in[1];  // [1024,3072]
    const float* bqkv = (const float*)d_in[2];  // [3072]
    const float* Wout = (const float*)d_in[3];  // [1024,1024]
    const float* bout = (const float*)d_in[4];  // [1024]
    float* out = (float*)d_out;                 // [8192,1024] fp32

    s16* ws   = (s16*)d_ws;
    s16* qkv  = ws;                          // [8192,3072] bf16
    s16* attn = qkv + (size_t)8192 * 3072;   // [8192,1024] bf16
    s16* wtq  = attn + (size_t)8192 * 1024;  // [3072,1024] bf16
    s16* wto  = wtq + (size_t)3072 * 1024;   // [1024,1024] bf16

    transpose_cast<<<dim3(3072 / 32, 1024 / 32), dim3(32, 8), 0, stream>>>(Wqkv, wtq, 1024, 3072);
    transpose_cast<<<dim3(1024 / 32, 1024 / 32), dim3(32, 8), 0, stream>>>(Wout, wto, 1024, 1024);
    gemm_bt_bias<true, false><<<dim3(3072 / 128, 8192 / 128), 256, 0, stream>>>(
        x, wtq, bqkv, qkv, 8192, 3072, 1024);
    attn_fwd<<<dim3(16, 64), 256, 0, stream>>>(qkv, attn);
    gemm_bt_bias<false, true><<<dim3(1024 / 128, 8192 / 128), 256, 0, stream>>>(
        attn, wto, bout, out, 8192, 1024, 1024);
}

// Round 8
// 278.824 us; speedup vs baseline: 1.2421x; 1.2421x over previous
//
#include <hip/hip_runtime.h>

// MultiHeadSelfAttention: B=4, S=2048, D=1024, H=16, HD=64, causal. fp32 I/O, bf16 MFMA.
// R8 = R5 baseline (paired-uniform attn grid, async GEMMs, pre-cast x) with ONE attn
// change: compute S^T = K Q^T (16x16x32). C-layout then gives each lane 4 consecutive
// keys for a fixed q => P^T round-trip is 8 conflict-free b64 stores + 8 b128 reads
// (was 32 8-way-conflicted b16 stores), epilogue is 8 b64 stores (was 32 b16),
// l-reduction is 2 shuffles/phase (was 32).

typedef short s16;
typedef __attribute__((ext_vector_type(4))) short s16x4;
typedef __attribute__((ext_vector_type(8))) short bf16x8;
typedef __attribute__((ext_vector_type(4))) float f32x4;

__device__ __forceinline__ s16 f2bf(float f) {
    union { float f; unsigned int i; } v;
    v.f = f;
    unsigned int r = v.i + 0x7fffu + ((v.i >> 16) & 1u);  // RNE
    return (s16)(r >> 16);
}

// pack two fp32 -> bf16x2 dword (round-half-up)
__device__ __forceinline__ unsigned pack_bf16(float a, float b) {
    union { float f; unsigned u; } x, y;
    x.f = a; y.f = b;
    return __byte_perm(x.u + 0x8000u, y.u + 0x8000u, 0x7632);
}

__device__ __forceinline__ void load_lds16(const s16* g, s16* lds_base) {
    __builtin_amdgcn_global_load_lds(
        (const __attribute__((address_space(1))) void*)g,
        (__attribute__((address_space(3))) void*)lds_base, 16, 0, 0);
}

// ---------------------------------------------------------------------------
// fp32 -> bf16 elementwise cast
// ---------------------------------------------------------------------------
__global__ void cast_f32_bf16(const float* __restrict__ in, s16* __restrict__ out) {
    const int i = (blockIdx.x * 256 + threadIdx.x) * 4;
    const float4 f = *(const float4*)(in + i);
    s16x4 r = {f2bf(f.x), f2bf(f.y), f2bf(f.z), f2bf(f.w)};
    *(s16x4*)(out + i) = r;
}

// ---------------------------------------------------------------------------
// Transpose + cast: fp32 [R,C] -> bf16 [C,R]
// ---------------------------------------------------------------------------
__global__ void transpose_cast(const float* __restrict__ in,
                               s16* __restrict__ out, int R, int C) {
    __shared__ float tile[32][33];
    const int cb = blockIdx.x * 32, rb = blockIdx.y * 32;
    const int tx = threadIdx.x, ty = threadIdx.y;  // 32 x 8
#pragma unroll
    for (int i = 0; i < 32; i += 8)
        tile[ty + i][tx] = in[(size_t)(rb + ty + i) * C + cb + tx];
    __syncthreads();
#pragma unroll
    for (int i = 0; i < 32; i += 8)
        out[(size_t)(cb + ty + i) * R + rb + tx] = f2bf(tile[tx][ty + i]);
}

// ---------------------------------------------------------------------------
// C[M,N] = A[M,K] @ Bt[N,K]^T + bias[N]. A,Bt bf16; C fp32 or bf16.
// m97 structure: 128x128 tile, BK=32, global_load_lds width-16 staging. (R5-proven)
// ---------------------------------------------------------------------------
template <bool OUT_F32>
__global__ __launch_bounds__(256) void gemm_bt_bias(
    const s16* __restrict__ A,
    const s16* __restrict__ Bt,
    const float* __restrict__ bias,
    void* __restrict__ Cv,
    int M, int N, int K) {
    __shared__ __attribute__((aligned(16))) s16 As[128 * 32];
    __shared__ __attribute__((aligned(16))) s16 Bs[128 * 32];

    const int tid  = threadIdx.x;
    const int lane = tid & 63;
    const int wave = tid >> 6;
    const int l15  = lane & 15;
    const int quad = lane >> 4;
    const int m0 = blockIdx.y * 128;
    const int n0 = blockIdx.x * 128;
    const int wm = (wave & 1) * 64;
    const int wn = (wave >> 1) * 64;

    f32x4 acc[4][4];
#pragma unroll
    for (int i = 0; i < 4; ++i)
#pragma unroll
        for (int j = 0; j < 4; ++j)
            acc[i][j] = (f32x4){0.f, 0.f, 0.f, 0.f};

    const int r_a = tid >> 2;  // 0..63: row within 64-row chunk; 4 lanes/row
    const int kp  = tid & 3;

    for (int k0 = 0; k0 < K; k0 += 32) {
        __syncthreads();  // prev iteration's LDS reads done
#pragma unroll
        for (int c = 0; c < 2; ++c) {
            load_lds16(A  + (size_t)(m0 + c * 64 + r_a) * K + k0 + kp * 8, As + c * 2048 + wave * 512);
            load_lds16(Bt + (size_t)(n0 + c * 64 + r_a) * K + k0 + kp * 8, Bs + c * 2048 + wave * 512);
        }
        __syncthreads();  // vmcnt(0) drain -> staged data visible

        bf16x8 af[4], bfv[4];
#pragma unroll
        for (int mt = 0; mt < 4; ++mt)
            af[mt] = *(const bf16x8*)(As + (wm + mt * 16 + l15) * 32 + quad * 8);
#pragma unroll
        for (int nt = 0; nt < 4; ++nt)
            bfv[nt] = *(const bf16x8*)(Bs + (wn + nt * 16 + l15) * 32 + quad * 8);
#pragma unroll
        for (int mt = 0; mt < 4; ++mt)
#pragma unroll
            for (int nt = 0; nt < 4; ++nt)
                acc[mt][nt] = __builtin_amdgcn_mfma_f32_16x16x32_bf16(af[mt], bfv[nt], acc[mt][nt], 0, 0, 0);
    }

#pragma unroll
    for (int nt = 0; nt < 4; ++nt) {
        const int col = n0 + wn + nt * 16 + l15;
        const float bv = bias[col];
#pragma unroll
        for (int mt = 0; mt < 4; ++mt) {
            const int rowb = m0 + wm + mt * 16 + quad * 4;
#pragma unroll
            for (int r = 0; r < 4; ++r) {
                const float v = acc[mt][nt][r] + bv;
                if constexpr (OUT_F32)
                    ((float*)Cv)[(size_t)(rowb + r) * N + col] = v;
                else
                    ((s16*)Cv)[(size_t)(rowb + r) * N + col] = f2bf(v);
            }
        }
    }
}

// ---------------------------------------------------------------------------
// Flash attention (causal), fixed-M softmax, S^T formulation.
// Block = (bh, q-tile pair {i, 15-i}) -> uniform 36 key-tiles; 4 waves x 32 q.
// St = K Q^T per 16x16 subtile: A = K-frag (same read as R5), B = Q^T (register
// content identical to R5's qf). C-layout: q = l15, key = quad*4+r.
// PT per-wave [32 q][88]: b64 stores / b128 reads, bank-verified conflict-free.
// O^T = V^T P^T: A = V^T-frag (R5's swizzled Vt), B = P^T from PT.
// ---------------------------------------------------------------------------
__global__ __launch_bounds__(256) void attn_fwd(
    const s16* __restrict__ qkv,
    s16* __restrict__ attn) {
    __shared__ __attribute__((aligned(16))) s16 Ks[64 * 72];
    __shared__ __attribute__((aligned(16))) s16 Vt[64 * 72];
    __shared__ __attribute__((aligned(16))) s16 PT[4][32][88];

    const int tid  = threadIdx.x;
    const int lane = tid & 63;
    const int wave = tid >> 6;
    const int l15  = lane & 15;
    const int quad = lane >> 4;
    const int bh = blockIdx.y;
    const size_t rowbase = (size_t)(bh >> 4) * 2048;
    const int hoff = (bh & 15) * 64;
    const int kp  = tid >> 3;  // 0..31: staged key-pair {2kp, 2kp+1}
    const int p_s = tid & 7;   // hd granule
    const int kg  = kp >> 2;   // key granule of this thread's pair

    const float C2 = 0.18033688011112042f;  // 0.125 * log2(e)
    const float M2 = 12.0f;                 // fixed shift (softmax shift-invariant)

    for (int phase = 0; phase < 2; ++phase) {
        const int qt = phase ? 15 - (int)blockIdx.x : (int)blockIdx.x;
        const int wq = qt * 128 + wave * 32;

        // Q fragments: lane holds Q[q = wq + qs*16 + l15][d = ks*32 + quad*8 + j]
        bf16x8 qf[2][2];
#pragma unroll
        for (int qs = 0; qs < 2; ++qs)
#pragma unroll
            for (int ks = 0; ks < 2; ++ks)
                qf[qs][ks] = *(const bf16x8*)(qkv + (rowbase + wq + qs * 16 + l15) * 3072 + hoff + ks * 32 + quad * 8);

        float l_lane[2] = {0.f, 0.f};
        f32x4 o[2][4];  // [qs][hs]; C-layout: q-col = l15, hd-row = hs*16 + quad*4 + r
#pragma unroll
        for (int qs = 0; qs < 2; ++qs)
#pragma unroll
            for (int hs = 0; hs < 4; ++hs)
                o[qs][hs] = (f32x4){0.f, 0.f, 0.f, 0.f};

        const int nkt = qt * 2 + 2;
        // prefetch tile 0 K/V
        bf16x8 kv[2], vv[2];
#pragma unroll
        for (int dk = 0; dk < 2; ++dk) {
            const s16* g = qkv + (rowbase + 2 * kp + dk) * 3072 + hoff + p_s * 8;
            kv[dk] = *(const bf16x8*)(g + 1024);
            vv[dk] = *(const bf16x8*)(g + 2048);
        }

        for (int kt = 0; kt < nkt; ++kt) {
            const int k0 = kt * 64;
            __syncthreads();  // prev iteration's LDS reads done
#pragma unroll
            for (int dk = 0; dk < 2; ++dk)  // K natural layout (R5-proven)
                *(bf16x8*)(Ks + (2 * kp + dk) * 72 + p_s * 8) = kv[dk];
#pragma unroll
            for (int j = 0; j < 8; ++j) {   // V^T swizzled, key-pair b32 (R7-verified)
                const unsigned dw = (unsigned)(unsigned short)vv[0][j] |
                                    ((unsigned)(unsigned short)vv[1][j] << 16);
                *(unsigned*)(Vt + (p_s * 8 + j) * 72 + ((kg ^ p_s) << 3) + (2 * kp & 7)) = dw;
            }
            __syncthreads();

            if (kt + 1 < nkt) {  // prefetch next tile under compute
#pragma unroll
                for (int dk = 0; dk < 2; ++dk) {
                    const s16* g = qkv + (rowbase + k0 + 64 + 2 * kp + dk) * 3072 + hoff + p_s * 8;
                    kv[dk] = *(const bf16x8*)(g + 1024);
                    vv[dk] = *(const bf16x8*)(g + 2048);
                }
            }

            if (k0 > wq + 31) continue;  // fully masked for this wave

            // S^T = K Q^T : st[qs][kb], key subtiles kb of 16
            f32x4 st[2][4];
#pragma unroll
            for (int qs = 0; qs < 2; ++qs)
#pragma unroll
                for (int kb = 0; kb < 4; ++kb)
                    st[qs][kb] = (f32x4){0.f, 0.f, 0.f, 0.f};
#pragma unroll
            for (int kb = 0; kb < 4; ++kb)
#pragma unroll
                for (int ks = 0; ks < 2; ++ks) {
                    const bf16x8 kf = *(const bf16x8*)(Ks + (kb * 16 + l15) * 72 + ks * 32 + quad * 8);
#pragma unroll
                    for (int qs = 0; qs < 2; ++qs)
                        st[qs][kb] = __builtin_amdgcn_mfma_f32_16x16x32_bf16(kf, qf[qs][ks], st[qs][kb], 0, 0, 0);
                }

            // softmax (fixed-M) + P^T -> PT (b64, conflict-free)
            const bool edge = (k0 + 63 > wq);
#pragma unroll
            for (int qs = 0; qs < 2; ++qs) {
                const int q = wq + qs * 16 + l15;
#pragma unroll
                for (int kb = 0; kb < 4; ++kb) {
                    float p4[4];
#pragma unroll
                    for (int r = 0; r < 4; ++r) {
                        float t = fmaf(st[qs][kb][r], C2, -M2);
                        if (edge) {
                            const int key = k0 + kb * 16 + quad * 4 + r;
                            t = (key <= q) ? t : -150.f;  // exp2(-150) == 0
                        }
                        p4[r] = __builtin_amdgcn_exp2f(t);
                        l_lane[qs] += p4[r];
                    }
                    uint2 dd;
                    dd.x = pack_bf16(p4[0], p4[1]);
                    dd.y = pack_bf16(p4[2], p4[3]);
                    *(uint2*)(&PT[wave][qs * 16 + l15][kb * 16 + quad * 4]) = dd;
                }
            }

            // O^T += V^T P^T
#pragma unroll
            for (int kk = 0; kk < 2; ++kk) {
                bf16x8 pf[2];
#pragma unroll
                for (int qs = 0; qs < 2; ++qs)
                    pf[qs] = *(const bf16x8*)(&PT[wave][qs * 16 + l15][kk * 32 + quad * 8]);
#pragma unroll
                for (int hs = 0; hs < 4; ++hs) {
                    const bf16x8 vf = *(const bf16x8*)(
                        Vt + (hs * 16 + l15) * 72 + (((kk * 4 + quad) ^ (2 * hs + (l15 >> 3))) << 3));
#pragma unroll
                    for (int qs = 0; qs < 2; ++qs)
                        o[qs][hs] = __builtin_amdgcn_mfma_f32_16x16x32_bf16(vf, pf[qs], o[qs][hs], 0, 0, 0);
                }
            }
        }

        // l: sum across the 4 quads (lanes with same l15)
        float rl[2];
#pragma unroll
        for (int qs = 0; qs < 2; ++qs) {
            float l = l_lane[qs];
            l += __shfl_xor(l, 16);
            l += __shfl_xor(l, 32);
            rl[qs] = 1.f / l;
        }

        // epilogue: O^T[hd][q] -> attn[q][hoff+hd]; 4 consecutive hd per reg-quad -> b64
#pragma unroll
        for (int qs = 0; qs < 2; ++qs) {
            const int q = wq + qs * 16 + l15;
#pragma unroll
            for (int hs = 0; hs < 4; ++hs) {
                uint2 dd;
                dd.x = pack_bf16(o[qs][hs][0] * rl[qs], o[qs][hs][1] * rl[qs]);
                dd.y = pack_bf16(o[qs][hs][2] * rl[qs], o[qs][hs][3] * rl[qs]);
                *(uint2*)(attn + (rowbase + q) * 1024 + hoff + hs * 16 + quad * 4) = dd;
            }
        }
    }
}

// ---------------------------------------------------------------------------
extern "C" void kernel_launch(void* const* d_in, const int* in_sizes, int n_in,
                              void* d_out, int out_size, void* d_ws, size_t ws_size,
                              hipStream_t stream) {
    const float* x    = (const float*)d_in[0];  // [8192,1024]
    const float* Wqkv = (const float*)d_in[1];  // [1024,3072]
    const float* bqkv = (const float*)d_in[2];  // [3072]
    const float* Wout = (const float*)d_in[3];  // [1024,1024]
    const float* bout = (const float*)d_in[4];  // [1024]
    float* out = (float*)d_out;                 // [8192,1024] fp32

    s16* ws   = (s16*)d_ws;
    s16* qkv  = ws;                          // [8192,3072] bf16
    s16* xba  = qkv + (size_t)8192 * 3072;   // [8192,1024] bf16: x-cast, later attn output
    s16* wtq  = xba + (size_t)8192 * 1024;   // [3072,1024] bf16
    s16* wto  = wtq + (size_t)3072 * 1024;   // [1024,1024] bf16

    cast_f32_bf16<<<8192, 256, 0, stream>>>(x, xba);
    transpose_cast<<<dim3(3072 / 32, 1024 / 32), dim3(32, 8), 0, stream>>>(Wqkv, wtq, 1024, 3072);
    transpose_cast<<<dim3(1024 / 32, 1024 / 32), dim3(32, 8), 0, stream>>>(Wout, wto, 1024, 1024);
    gemm_bt_bias<false><<<dim3(3072 / 128, 8192 / 128), 256, 0, stream>>>(
        xba, wtq, bqkv, qkv, 8192, 3072, 1024);
    attn_fwd<<<dim3(8, 64), 256, 0, stream>>>(qkv, xba);  // xba dead; reused as attn buf
    gemm_bt_bias<true><<<dim3(1024 / 128, 8192 / 128), 256, 0, stream>>>(
        xba, wto, bout, out, 8192, 1024, 1024);
}